// Round 1
// baseline (502.667 us; speedup 1.0000x reference)
//
#include <hip/hip_runtime.h>
#include <hip/hip_bf16.h>

// Problem constants (fixed by the reference)
#define V 3
#define A 4
#define NN 50000
#define C 128
#define C4 32            // C in float4 units
#define CHUNKS 128       // row chunks per (v,a) in the column-sum kernel

// ---------------------------------------------------------------------------
// K1: s_sum[v,a,c] = sum_n x[v,a,n,c]   (atomic partial sums per chunk)
// grid = (CHUNKS, V*A), block = 256
// ---------------------------------------------------------------------------
__global__ void k_colsum(const float* __restrict__ x, float* __restrict__ s_sum) {
    const int va    = blockIdx.y;
    const int chunk = blockIdx.x;
    const int rowsPer = (NN + CHUNKS - 1) / CHUNKS;
    const int n0 = chunk * rowsPer;
    const int n1 = (n0 + rowsPer < NN) ? (n0 + rowsPer) : NN;

    const int lane4 = threadIdx.x & 31;   // which float4 within the row
    const int rowIn = threadIdx.x >> 5;   // 0..7

    const float4* xp = (const float4*)(x + (size_t)va * NN * C);
    float4 acc = {0.f, 0.f, 0.f, 0.f};
    for (int n = n0 + rowIn; n < n1; n += 8) {
        float4 v = xp[(size_t)n * C4 + lane4];
        acc.x += v.x; acc.y += v.y; acc.z += v.z; acc.w += v.w;
    }

    __shared__ float4 red[256];
    red[threadIdx.x] = acc;
    __syncthreads();
    if (threadIdx.x < 32) {
        float4 t = red[threadIdx.x];
        #pragma unroll
        for (int r = 1; r < 8; r++) {
            float4 o = red[threadIdx.x + 32 * r];
            t.x += o.x; t.y += o.y; t.z += o.z; t.w += o.w;
        }
        float* dst = s_sum + va * C + lane4 * 4;
        atomicAdd(dst + 0, t.x);
        atomicAdd(dst + 1, t.y);
        atomicAdd(dst + 2, t.z);
        atomicAdd(dst + 3, t.w);
    }
}

// ---------------------------------------------------------------------------
// K2: t[v,a,c] = sum_d (s_sum[v,a,d]/N) * W[v,d,c];  c0[v,a] = sbar . b[v]
// grid = V*A blocks, block = 128
// ---------------------------------------------------------------------------
__global__ void k_tvec(const float* __restrict__ s_sum, const float* __restrict__ W,
                       const float* __restrict__ b, float* __restrict__ t,
                       float* __restrict__ c0) {
    const int va = blockIdx.x;       // 0..11
    const int v  = va / A;
    const int c  = threadIdx.x;      // 0..127

    __shared__ float sb[C];
    __shared__ float pb[C];
    const float invN = 1.0f / (float)NN;
    sb[c] = s_sum[va * C + c] * invN;
    __syncthreads();

    const float* Wv = W + (size_t)v * C * C;
    float acc = 0.f;
    #pragma unroll 8
    for (int d = 0; d < C; d++) acc += sb[d] * Wv[d * C + c];
    t[va * C + c] = acc;

    pb[c] = sb[c] * b[v * C + c];
    __syncthreads();
    if (c == 0) {
        float s = 0.f;
        for (int d = 0; d < C; d++) s += pb[d];
        c0[va] = s;
    }
}

// ---------------------------------------------------------------------------
// K3: fused scores -> tanh -> softmax over V -> weighted combine.
// One 32-lane group per node n. grid = (N/8, A), block = 256 (8 groups).
// ---------------------------------------------------------------------------
__global__ void k_main(const float* __restrict__ x, const float* __restrict__ t,
                       const float* __restrict__ c0, float* __restrict__ out) {
    const int lane = threadIdx.x & 31;
    const int grp  = threadIdx.x >> 5;
    const int n    = blockIdx.x * 8 + grp;
    const int a    = blockIdx.y;

    const size_t vstride = (size_t)A * NN * C4;  // view stride, float4 units
    const float4* xp = (const float4*)x;
    const size_t base = ((size_t)a * NN + n) * C4 + lane;

    float4 x0 = xp[base];
    float4 x1 = xp[base + vstride];
    float4 x2 = xp[base + 2 * vstride];

    const float4* tp = (const float4*)t;
    float4 t0 = tp[(0 * A + a) * C4 + lane];
    float4 t1 = tp[(1 * A + a) * C4 + lane];
    float4 t2 = tp[(2 * A + a) * C4 + lane];

    float d0 = x0.x * t0.x + x0.y * t0.y + x0.z * t0.z + x0.w * t0.w;
    float d1 = x1.x * t1.x + x1.y * t1.y + x1.z * t1.z + x1.w * t1.w;
    float d2 = x2.x * t2.x + x2.y * t2.y + x2.z * t2.z + x2.w * t2.w;

    // butterfly reduce within the 32-lane group
    #pragma unroll
    for (int off = 16; off > 0; off >>= 1) {
        d0 += __shfl_xor(d0, off, 32);
        d1 += __shfl_xor(d1, off, 32);
        d2 += __shfl_xor(d2, off, 32);
    }

    float s0 = tanhf(d0 + c0[0 * A + a]);
    float s1 = tanhf(d1 + c0[1 * A + a]);
    float s2 = tanhf(d2 + c0[2 * A + a]);

    float m  = fmaxf(s0, fmaxf(s1, s2));
    float e0 = expf(s0 - m), e1 = expf(s1 - m), e2 = expf(s2 - m);
    float inv = 1.0f / (e0 + e1 + e2);
    float w0 = e0 * inv, w1 = e1 * inv, w2 = e2 * inv;

    float4 o;
    o.x = w0 * x0.x + w1 * x1.x + w2 * x2.x;
    o.y = w0 * x0.y + w1 * x1.y + w2 * x2.y;
    o.z = w0 * x0.z + w1 * x1.z + w2 * x2.z;
    o.w = w0 * x0.w + w1 * x1.w + w2 * x2.w;

    ((float4*)out)[((size_t)a * NN + n) * C4 + lane] = o;
}

// ---------------------------------------------------------------------------
extern "C" void kernel_launch(void* const* d_in, const int* in_sizes, int n_in,
                              void* d_out, int out_size, void* d_ws, size_t ws_size,
                              hipStream_t stream) {
    const float* x = (const float*)d_in[0];
    const float* W = (const float*)d_in[1];
    const float* b = (const float*)d_in[2];
    float* out = (float*)d_out;

    float* s_sum = (float*)d_ws;            // V*A*C floats
    float* t     = s_sum + V * A * C;       // V*A*C floats
    float* c0    = t + V * A * C;           // V*A floats

    hipMemsetAsync(s_sum, 0, V * A * C * sizeof(float), stream);

    k_colsum<<<dim3(CHUNKS, V * A), 256, 0, stream>>>(x, s_sum);
    k_tvec<<<V * A, C, 0, stream>>>(s_sum, W, b, t, c0);
    k_main<<<dim3(NN / 8, A), 256, 0, stream>>>(x, t, c0, out);
}